// Round 4
// baseline (1051.638 us; speedup 1.0000x reference)
//
#include <hip/hip_runtime.h>

#define B_SZ 128
#define IN_CAPS 1152
#define N_CAPS 16
#define DIM 16

#define IPT 8                        // i's per block
#define ICN (IN_CAPS / IPT)          // 144
#define OUT_ELEMS (B_SZ * N_CAPS * DIM)  // 32768 floats = 128 KB per acc buffer

// Inline squash of one (b,n,:) row held in registers: v[e] = squash(s[e]) where
// s = accrow + Bb. Returns via out[16].
__device__ __forceinline__ void squash_row(const float* __restrict__ accrow,
                                           const float bb[16], float out[16])
{
    float s[16], s2 = 0.f;
    #pragma unroll
    for (int q = 0; q < 4; ++q) {
        float4 a = ((const float4*)accrow)[q];
        s[4*q+0] = a.x + bb[4*q+0]; s[4*q+1] = a.y + bb[4*q+1];
        s[4*q+2] = a.z + bb[4*q+2]; s[4*q+3] = a.w + bb[4*q+3];
    }
    #pragma unroll
    for (int e = 0; e < 16; ++e) s2 = fmaf(s[e], s[e], s2);
    float sc = sqrtf(s2) / (1.0f + s2);      // s2/(1+s2)/sqrt(s2)
    #pragma unroll
    for (int e = 0; e < 16; ++e) out[e] = s[e] * sc;
}

// Fused routing pass. thread = (n = tid&15, bh = tid>>4); owns b0 = bt*32+bh and
// b1 = b0+16. W is STREAMED through an 8-float window in the e-loop (R1-R3
// lesson: any long-lived W register array gets remat'd into L1 reloads by the
// compiler; accumulators can't be). pr (prev outputs) is computed in the
// prologue by squashing acc from the previous pass (fused squash — no separate
// kernel, no prev buffer) and pinned with asm so it can't be rematerialized.
// MODE 0: c = 1/16 (softmax of zeros), accumulate into accA.
// MODE 1: pr = squash(accA+B),                accumulate into accB.
// MODE 2: pr = squash(accA+B)+squash(accB+B), accumulate into accC.
template<int MODE>
__global__ __launch_bounds__(256) __attribute__((amdgpu_waves_per_eu(2, 3)))
void caps_pass(const float* __restrict__ x, const float* __restrict__ W,
               const float* __restrict__ Bb,
               const float* __restrict__ accA, const float* __restrict__ accB,
               float* __restrict__ accOut)
{
    const int tid = threadIdx.x;
    const int n   = tid & 15;
    const int bh  = tid >> 4;                 // 0..15
    const int i0  = blockIdx.x * IPT;
    const int b0  = blockIdx.y * 32 + bh;
    const int b1  = b0 + 16;

    float pr0[16], pr1[16];
    if (MODE > 0) {
        float bb[16];
        #pragma unroll
        for (int q = 0; q < 4; ++q) {
            float4 a = ((const float4*)(Bb + (n << 4)))[q];
            bb[4*q+0] = a.x; bb[4*q+1] = a.y; bb[4*q+2] = a.z; bb[4*q+3] = a.w;
        }
        squash_row(accA + ((size_t)b0 << 8) + (n << 4), bb, pr0);
        squash_row(accA + ((size_t)b1 << 8) + (n << 4), bb, pr1);
        if (MODE == 2) {
            float q0[16], q1[16];
            squash_row(accB + ((size_t)b0 << 8) + (n << 4), bb, q0);
            squash_row(accB + ((size_t)b1 << 8) + (n << 4), bb, q1);
            #pragma unroll
            for (int e = 0; e < 16; ++e) { pr0[e] += q0[e]; pr1[e] += q1[e]; }
        }
        // Pin: forbid remat (recomputing pr = global loads + squash per i-iter)
        #pragma unroll
        for (int e = 0; e < 16; ++e)
            asm volatile("" : "+v"(pr0[e]), "+v"(pr1[e]));
    }

    float acc0[16], acc1[16];
    #pragma unroll
    for (int e = 0; e < 16; ++e) { acc0[e] = 0.f; acc1[e] = 0.f; }

    const float* wbase = W + ((size_t)n * IN_CAPS + i0) * 128;  // W[n][i][e][d]

    for (int ii = 0; ii < IPT; ++ii) {
        const int i = i0 + ii;
        const float4* wp = (const float4*)(wbase + (size_t)ii * 128);

        const float4* xp0 = (const float4*)(x + ((size_t)b0 * IN_CAPS + i) * 8);
        const float4* xp1 = (const float4*)(x + ((size_t)b1 * IN_CAPS + i) * 8);
        float4 xa = xp0[0], xb = xp0[1], xc = xp1[0], xd = xp1[1];
        float xr0[8] = {xa.x, xa.y, xa.z, xa.w, xb.x, xb.y, xb.z, xb.w};
        float xr1[8] = {xc.x, xc.y, xc.z, xc.w, xd.x, xd.y, xd.z, xd.w};

        float hat0[16], hat1[16];
        float lg0 = 0.f, lg1 = 0.f;
        #pragma unroll
        for (int e = 0; e < 16; ++e) {
            float4 wa = wp[2*e], wb = wp[2*e+1];   // W streamed: 8-float window
            float wr[8] = {wa.x, wa.y, wa.z, wa.w, wb.x, wb.y, wb.z, wb.w};
            float h0 = 0.f, h1 = 0.f;
            #pragma unroll
            for (int d = 0; d < 8; ++d) {
                h0 = fmaf(xr0[d], wr[d], h0);
                h1 = fmaf(xr1[d], wr[d], h1);
            }
            hat0[e] = h0; hat1[e] = h1;
            if (MODE > 0) {
                lg0 = fmaf(pr0[e], h0, lg0);       // logit: in-thread e-dot
                lg1 = fmaf(pr1[e], h1, lg1);
            }
        }
        // Pin hat: recomputing it would mean re-streaming W (2x L1 traffic)
        #pragma unroll
        for (int e = 0; e < 16; ++e)
            asm volatile("" : "+v"(hat0[e]), "+v"(hat1[e]));

        float c0, c1;
        if (MODE > 0) {
            // softmax over n = lanes 0..15 (xor masks < 16 stay in the n-group)
            float m0 = lg0, m1 = lg1;
            #pragma unroll
            for (int msk = 8; msk >= 1; msk >>= 1) {
                m0 = fmaxf(m0, __shfl_xor(m0, msk));
                m1 = fmaxf(m1, __shfl_xor(m1, msk));
            }
            float p0 = __expf(lg0 - m0), p1 = __expf(lg1 - m1);
            float z0 = p0, z1 = p1;
            #pragma unroll
            for (int msk = 8; msk >= 1; msk >>= 1) {
                z0 += __shfl_xor(z0, msk);
                z1 += __shfl_xor(z1, msk);
            }
            c0 = p0 / z0; c1 = p1 / z1;
        } else {
            c0 = c1 = 1.0f / 16.0f;                // softmax of all-zero logits
        }

        #pragma unroll
        for (int e = 0; e < 16; ++e) {
            acc0[e] = fmaf(c0, hat0[e], acc0[e]);
            acc1[e] = fmaf(c1, hat1[e], acc1[e]);
        }
    }

    float* a0 = accOut + ((size_t)b0 << 8) + (n << 4);
    float* a1 = accOut + ((size_t)b1 << 8) + (n << 4);
    #pragma unroll
    for (int e = 0; e < 16; ++e) {
        atomicAdd(a0 + e, acc0[e]);
        atomicAdd(a1 + e, acc1[e]);
    }
}

// Final: out = squash(accC + B). g = b*256 + n*16 + e; squash sum over e via
// 16-lane shuffles.
__global__ __launch_bounds__(256)
void caps_final(const float* __restrict__ accC, const float* __restrict__ Bb,
                float* __restrict__ out)
{
    const int g = blockIdx.x * 256 + threadIdx.x;
    float t = accC[g] + Bb[g & 255];
    float s2 = t * t;
    #pragma unroll
    for (int msk = 8; msk >= 1; msk >>= 1)
        s2 += __shfl_xor(s2, msk);
    out[g] = t * (sqrtf(s2) / (1.0f + s2));
}

extern "C" void kernel_launch(void* const* d_in, const int* in_sizes, int n_in,
                              void* d_out, int out_size, void* d_ws, size_t ws_size,
                              hipStream_t stream)
{
    const float* x  = (const float*)d_in[0];   // [128,1152,8]
    const float* W  = (const float*)d_in[1];   // [16,1152,16,8]
    const float* Bb = (const float*)d_in[2];   // [16,16]
    float* out = (float*)d_out;                // [128,16,16]

    float* accA = (float*)d_ws;                // 3 x 128 KB atomic accumulators
    float* accB = accA + OUT_ELEMS;
    float* accC = accB + OUT_ELEMS;

    hipMemsetAsync(accA, 0, 3 * OUT_ELEMS * sizeof(float), stream);

    dim3 pg(ICN, B_SZ / 32);   // 144 x 4 = 576 blocks

    caps_pass<0><<<pg, 256, 0, stream>>>(x, W, Bb, nullptr, nullptr, accA);
    caps_pass<1><<<pg, 256, 0, stream>>>(x, W, Bb, accA,    nullptr, accB);
    caps_pass<2><<<pg, 256, 0, stream>>>(x, W, Bb, accA,    accB,    accC);
    caps_final<<<OUT_ELEMS / 256, 256, 0, stream>>>(accC, Bb, out);
}

// Round 5
// 365.002 us; speedup vs baseline: 2.8812x; 2.8812x over previous
//
#include <hip/hip_runtime.h>

#define B_SZ 128
#define IN_CAPS 1152
#define N_CAPS 16
#define DIM 16

#define IPT 8                        // i's per pass-block
#define ICN (IN_CAPS / IPT)          // 144 partial slices
#define OUT_ELEMS (B_SZ * N_CAPS * DIM)   // 32768 floats (one acc buffer)
#define SLICE OUT_ELEMS              // floats per partial slice

// Inline squash of one (b,n,:) row: out = squash(accrow + bb).
__device__ __forceinline__ void squash_row(const float* __restrict__ accrow,
                                           const float bb[16], float out[16])
{
    float s[16], s2 = 0.f;
    #pragma unroll
    for (int q = 0; q < 4; ++q) {
        float4 a = ((const float4*)accrow)[q];
        s[4*q+0] = a.x + bb[4*q+0]; s[4*q+1] = a.y + bb[4*q+1];
        s[4*q+2] = a.z + bb[4*q+2]; s[4*q+3] = a.w + bb[4*q+3];
    }
    #pragma unroll
    for (int e = 0; e < 16; ++e) s2 = fmaf(s[e], s[e], s2);
    float sc = sqrtf(s2) / (1.0f + s2);      // s2/(1+s2)/sqrt(s2)
    #pragma unroll
    for (int e = 0; e < 16; ++e) out[e] = s[e] * sc;
}

// Fused routing pass (R4 compute structure — W streamed, reg accumulators,
// softmax over n in-wave). R4 lesson: NO GLOBAL ATOMICS — device-scope fp32
// atomicAdd write-throughs ~32B/op past the non-coherent L2s (147 MB tail,
// 330 us). Epilogue now writes a deterministic partial slice per block.
// thread = (n = tid&15, bh = tid>>4); owns b0 = bt*32+bh and b1 = b0+16.
// MODE 0: c = 1/16 (softmax of zeros).  MODE 1: pr = squash(accA+B).
// MODE 2: pr = squash(accA+B) + squash(accB+B).
template<int MODE>
__global__ __launch_bounds__(256)
void caps_pass(const float* __restrict__ x, const float* __restrict__ W,
               const float* __restrict__ Bb,
               const float* __restrict__ accA, const float* __restrict__ accB,
               float* __restrict__ partial)
{
    const int tid = threadIdx.x;
    const int n   = tid & 15;
    const int bh  = tid >> 4;                 // 0..15
    const int ic  = blockIdx.x;               // 0..143
    const int i0  = ic * IPT;
    const int b0  = blockIdx.y * 32 + bh;
    const int b1  = b0 + 16;

    float pr0[16], pr1[16];
    if (MODE > 0) {
        float bb[16];
        #pragma unroll
        for (int q = 0; q < 4; ++q) {
            float4 a = ((const float4*)(Bb + (n << 4)))[q];
            bb[4*q+0] = a.x; bb[4*q+1] = a.y; bb[4*q+2] = a.z; bb[4*q+3] = a.w;
        }
        squash_row(accA + ((size_t)b0 << 8) + (n << 4), bb, pr0);
        squash_row(accA + ((size_t)b1 << 8) + (n << 4), bb, pr1);
        if (MODE == 2) {
            float q0[16], q1[16];
            squash_row(accB + ((size_t)b0 << 8) + (n << 4), bb, q0);
            squash_row(accB + ((size_t)b1 << 8) + (n << 4), bb, q1);
            #pragma unroll
            for (int e = 0; e < 16; ++e) { pr0[e] += q0[e]; pr1[e] += q1[e]; }
        }
        // Pin: forbid remat (recomputing pr would re-load + re-squash per iter)
        #pragma unroll
        for (int e = 0; e < 16; ++e)
            asm volatile("" : "+v"(pr0[e]), "+v"(pr1[e]));
    }

    float acc0[16], acc1[16];
    #pragma unroll
    for (int e = 0; e < 16; ++e) { acc0[e] = 0.f; acc1[e] = 0.f; }

    const float* wbase = W + ((size_t)n * IN_CAPS + i0) * 128;  // W[n][i][e][d]

    for (int ii = 0; ii < IPT; ++ii) {
        const int i = i0 + ii;
        const float4* wp = (const float4*)(wbase + (size_t)ii * 128);

        const float4* xp0 = (const float4*)(x + ((size_t)b0 * IN_CAPS + i) * 8);
        const float4* xp1 = (const float4*)(x + ((size_t)b1 * IN_CAPS + i) * 8);
        float4 xa = xp0[0], xb = xp0[1], xc = xp1[0], xd = xp1[1];
        float xr0[8] = {xa.x, xa.y, xa.z, xa.w, xb.x, xb.y, xb.z, xb.w};
        float xr1[8] = {xc.x, xc.y, xc.z, xc.w, xd.x, xd.y, xd.z, xd.w};

        float hat0[16], hat1[16];
        float lg0 = 0.f, lg1 = 0.f;
        #pragma unroll
        for (int e = 0; e < 16; ++e) {
            float4 wa = wp[2*e], wb = wp[2*e+1];   // W streamed: 8-float window
            float wr[8] = {wa.x, wa.y, wa.z, wa.w, wb.x, wb.y, wb.z, wb.w};
            float h0 = 0.f, h1 = 0.f;
            #pragma unroll
            for (int d = 0; d < 8; ++d) {
                h0 = fmaf(xr0[d], wr[d], h0);
                h1 = fmaf(xr1[d], wr[d], h1);
            }
            hat0[e] = h0; hat1[e] = h1;
            if (MODE > 0) {
                lg0 = fmaf(pr0[e], h0, lg0);       // logit: in-thread e-dot
                lg1 = fmaf(pr1[e], h1, lg1);
            }
        }
        // Pin hat: recomputing it would mean re-streaming W
        #pragma unroll
        for (int e = 0; e < 16; ++e)
            asm volatile("" : "+v"(hat0[e]), "+v"(hat1[e]));

        float c0, c1;
        if (MODE > 0) {
            // softmax over n = low-4 lane bits (partners share bh, hence b)
            float m0 = lg0, m1 = lg1;
            #pragma unroll
            for (int msk = 8; msk >= 1; msk >>= 1) {
                m0 = fmaxf(m0, __shfl_xor(m0, msk));
                m1 = fmaxf(m1, __shfl_xor(m1, msk));
            }
            float p0 = __expf(lg0 - m0), p1 = __expf(lg1 - m1);
            float z0 = p0, z1 = p1;
            #pragma unroll
            for (int msk = 8; msk >= 1; msk >>= 1) {
                z0 += __shfl_xor(z0, msk);
                z1 += __shfl_xor(z1, msk);
            }
            c0 = p0 / z0; c1 = p1 / z1;
        } else {
            c0 = c1 = 1.0f / 16.0f;                // softmax of all-zero logits
        }

        #pragma unroll
        for (int e = 0; e < 16; ++e) {
            acc0[e] = fmaf(c0, hat0[e], acc0[e]);
            acc1[e] = fmaf(c1, hat1[e], acc1[e]);
        }
    }

    // Deterministic partial write: partial[ic][b][n][e], 8 dwordx4 stores.
    float* p0 = partial + ((size_t)ic << 15) + ((size_t)b0 << 8) + (n << 4);
    float* p1 = partial + ((size_t)ic << 15) + ((size_t)b1 << 8) + (n << 4);
    #pragma unroll
    for (int q = 0; q < 4; ++q) {
        ((float4*)p0)[q] = make_float4(acc0[4*q], acc0[4*q+1], acc0[4*q+2], acc0[4*q+3]);
        ((float4*)p1)[q] = make_float4(acc1[4*q], acc1[4*q+1], acc1[4*q+2], acc1[4*q+3]);
    }
}

// Reduce 144 partial slices -> acc (raw sums).  FINAL: instead add B, squash,
// write d_out. float4 granularity: pos = b*64 + n*4 + eg (8192 positions).
// 128 blocks x 256 thr: 64 positions/block, 4 groups x 36 slices each.
template<bool FINAL>
__global__ __launch_bounds__(256)
void caps_reduce(const float4* __restrict__ partial, const float* __restrict__ Bb,
                 float4* __restrict__ acc, float4* __restrict__ out)
{
    const int tid = threadIdx.x;
    const int ps  = tid & 63;
    const int pos = blockIdx.x * 64 + ps;
    const int grp = tid >> 6;

    float4 s = make_float4(0.f, 0.f, 0.f, 0.f);
    #pragma unroll
    for (int k = 0; k < ICN / 4; ++k) {
        float4 v = partial[(size_t)(grp * (ICN / 4) + k) * (SLICE / 4) + pos];
        s.x += v.x; s.y += v.y; s.z += v.z; s.w += v.w;
    }

    __shared__ float4 red[4][64];
    red[grp][ps] = s;
    __syncthreads();

    if (tid < 64) {
        float4 a = red[0][ps], b = red[1][ps], c = red[2][ps], d = red[3][ps];
        float4 t = make_float4(a.x + b.x + c.x + d.x, a.y + b.y + c.y + d.y,
                               a.z + b.z + c.z + d.z, a.w + b.w + c.w + d.w);
        if (!FINAL) {
            acc[pos] = t;
        } else {
            float4 bb = ((const float4*)Bb)[pos & 63];
            t.x += bb.x; t.y += bb.y; t.z += bb.z; t.w += bb.w;
            // e-row = 4 adjacent lanes (eg = pos&3): combine via shfl_xor(1,2)
            float s2 = t.x*t.x + t.y*t.y + t.z*t.z + t.w*t.w;
            s2 += __shfl_xor(s2, 1);
            s2 += __shfl_xor(s2, 2);
            float sc = sqrtf(s2) / (1.0f + s2);
            t.x *= sc; t.y *= sc; t.z *= sc; t.w *= sc;
            out[pos] = t;
        }
    }
}

extern "C" void kernel_launch(void* const* d_in, const int* in_sizes, int n_in,
                              void* d_out, int out_size, void* d_ws, size_t ws_size,
                              hipStream_t stream)
{
    const float* x  = (const float*)d_in[0];   // [128,1152,8]
    const float* W  = (const float*)d_in[1];   // [16,1152,16,8]
    const float* Bb = (const float*)d_in[2];   // [16,16]
    float4* out = (float4*)d_out;              // [128,16,16]

    float* accA    = (float*)d_ws;             // 128 KB
    float* accB    = accA + OUT_ELEMS;         // 128 KB
    float* partial = accB + OUT_ELEMS;         // 144 x 128 KB = 18 MB

    dim3 pg(ICN, B_SZ / 32);   // 144 x 4 = 576 blocks

    caps_pass<0><<<pg, 256, 0, stream>>>(x, W, Bb, nullptr, nullptr, partial);
    caps_reduce<false><<<128, 256, 0, stream>>>((const float4*)partial, Bb, (float4*)accA, nullptr);
    caps_pass<1><<<pg, 256, 0, stream>>>(x, W, Bb, accA, nullptr, partial);
    caps_reduce<false><<<128, 256, 0, stream>>>((const float4*)partial, Bb, (float4*)accB, nullptr);
    caps_pass<2><<<pg, 256, 0, stream>>>(x, W, Bb, accA, accB, partial);
    caps_reduce<true><<<128, 256, 0, stream>>>((const float4*)partial, Bb, nullptr, out);
}